// Round 5
// baseline (2490.981 us; speedup 1.0000x reference)
//
#include <hip/hip_runtime.h>
#include <hip/hip_bf16.h>
#include <math.h>

// Problem constants
#define NB 8
#define NSEQ 1024
#define M_ 1025                 // NSEQ + 1 (cls)
#define ROWS (NB * M_)          // 8200
#define DIMC 128
#define NHEADS 8
#define QKV3 3072               // 3*8*128
#define PEROWS (NB * NSEQ)      // 8192
#define ACS 1088                // adj_cls / vt padded column stride

typedef __attribute__((ext_vector_type(8))) short bf16x8;
typedef __attribute__((ext_vector_type(4))) float f32x4;

__device__ __forceinline__ float gelu_f(float x) {
  return 0.5f * x * (1.f + erff(x * 0.70710678118654752440f));
}

__device__ __forceinline__ unsigned short f2bf(float f) {
  __hip_bfloat16 h = __float2bfloat16(f);
  return *reinterpret_cast<unsigned short*>(&h);
}

__device__ __forceinline__ float bf2f(unsigned short u) {
  union { unsigned int i; float f; } c;
  c.i = ((unsigned int)u) << 16;
  return c.f;
}

// ---------------------------------------------------------------------------
// fp32 row-tiled GEMM (PE encoder + head only)
// ---------------------------------------------------------------------------
template<int TR>
__global__ __launch_bounds__(256) void rowgemm_k(
    const float* __restrict__ in, const float* __restrict__ W,
    const float* __restrict__ bias, const float* __restrict__ res,
    float* __restrict__ out, int rows, int K, int Nout, int act, int remap)
{
  extern __shared__ float s_in[];
  const int tid = threadIdx.x;
  const int r0 = blockIdx.x * TR;
  const int tot = TR * K;
  for (int idx = tid; idx < tot; idx += blockDim.x) {
    int r = idx / K;
    int k = idx - r * K;
    int gr = r0 + r;
    s_in[idx] = (gr < rows) ? in[(size_t)gr * K + k] : 0.f;
  }
  __syncthreads();
  const int j = blockIdx.y * blockDim.x + tid;
  if (j >= Nout) return;
  float acc[TR];
  const float bv = bias ? bias[j] : 0.f;
#pragma unroll
  for (int r = 0; r < TR; ++r) acc[r] = bv;
  for (int k = 0; k < K; ++k) {
    const float w = W[(size_t)k * Nout + j];
#pragma unroll
    for (int r = 0; r < TR; ++r) acc[r] = fmaf(s_in[r * K + k], w, acc[r]);
  }
  for (int r = 0; r < TR; ++r) {
    const int gr = r0 + r;
    if (gr >= rows) break;
    float v = acc[r];
    if (act == 1) v = gelu_f(v);
    if (res) v += res[(size_t)gr * Nout + j];
    const size_t orow = remap ? (size_t)(gr + gr / 1024 + 1) : (size_t)gr;
    out[orow * (size_t)Nout + j] = v;
  }
}

// ---------------------------------------------------------------------------
// bf16 MFMA GEMM: out = [act]( Xb @ Wt^T + bias ) [+ res]
// ---------------------------------------------------------------------------
template<int ACT, int OBF, int RES>
__global__ __launch_bounds__(256) void mgemm_k(
    const unsigned short* __restrict__ Xb, const unsigned short* __restrict__ Wt,
    const float* __restrict__ bias, const float* __restrict__ res,
    void* __restrict__ outp, int rows, int K, int N)
{
  __shared__ unsigned short sX[64][72];
  __shared__ unsigned short sW[64][72];
  const int tid = threadIdx.x;
  const int w = tid >> 6, lane = tid & 63;
  const int col = lane & 15, quad = lane >> 4;
  const int r0 = blockIdx.x * 64, n0 = blockIdx.y * 64;
  const int lr = tid >> 2, lc = tid & 3;
  const int xrow = min(r0 + lr, rows - 1);
  const unsigned short* xsrc = Xb + (size_t)xrow * K + lc * 8;
  const unsigned short* wsrc = Wt + (size_t)(n0 + lr) * K + lc * 8;

  f32x4 acc[4];
#pragma unroll
  for (int t = 0; t < 4; ++t) acc[t] = (f32x4){0.f, 0.f, 0.f, 0.f};

  for (int k0 = 0; k0 < K; k0 += 64) {
    __syncthreads();
    *(uint4*)&sX[lr][lc * 8]      = *(const uint4*)(xsrc + k0);
    *(uint4*)&sX[lr][lc * 8 + 32] = *(const uint4*)(xsrc + k0 + 32);
    *(uint4*)&sW[lr][lc * 8]      = *(const uint4*)(wsrc + k0);
    *(uint4*)&sW[lr][lc * 8 + 32] = *(const uint4*)(wsrc + k0 + 32);
    __syncthreads();
    const bf16x8 aX0 = *(const bf16x8*)&sX[w * 16 + col][quad * 8];
    const bf16x8 aX1 = *(const bf16x8*)&sX[w * 16 + col][32 + quad * 8];
#pragma unroll
    for (int t = 0; t < 4; ++t) {
      const bf16x8 bW0 = *(const bf16x8*)&sW[t * 16 + col][quad * 8];
      const bf16x8 bW1 = *(const bf16x8*)&sW[t * 16 + col][32 + quad * 8];
      acc[t] = __builtin_amdgcn_mfma_f32_16x16x32_bf16(aX0, bW0, acc[t], 0, 0, 0);
      acc[t] = __builtin_amdgcn_mfma_f32_16x16x32_bf16(aX1, bW1, acc[t], 0, 0, 0);
    }
  }
  const int gr_base = r0 + w * 16 + quad * 4;
#pragma unroll
  for (int t = 0; t < 4; ++t) {
    const int n = n0 + t * 16 + col;
    const float bv = bias ? bias[n] : 0.f;
#pragma unroll
    for (int r = 0; r < 4; ++r) {
      const int gr = gr_base + r;
      if (gr < rows) {
        float v = acc[t][r] + bv;
        if (ACT) v = gelu_f(v);
        if (RES) v += res[(size_t)gr * N + n];
        if (OBF) ((unsigned short*)outp)[(size_t)gr * N + n] = f2bf(v);
        else     ((float*)outp)[(size_t)gr * N + n] = v;
      }
    }
  }
}

// ---------------------------------------------------------------------------
// Wave-per-row LayerNorm; optional bf16 shadow out; optional fused gamma
// ---------------------------------------------------------------------------
__global__ __launch_bounds__(256) void ln_rows_k(
    const float* __restrict__ in, float* __restrict__ out,
    unsigned short* __restrict__ outb,
    const float* __restrict__ g, const float* __restrict__ b,
    const float* __restrict__ gw, const float* __restrict__ gb,
    float* __restrict__ gamout, int rows, int D)
{
  const int wv = (blockIdx.x * blockDim.x + threadIdx.x) >> 6;
  const int lane = threadIdx.x & 63;
  if (wv >= rows) return;
  const float* r = in + (size_t)wv * D;
  float s = 0.f;
  for (int d = lane; d < D; d += 64) s += r[d];
  for (int off = 32; off; off >>= 1) s += __shfl_down(s, off);
  const float mean = __shfl(s, 0) / (float)D;
  float v = 0.f;
  for (int d = lane; d < D; d += 64) { float t = r[d] - mean; v += t * t; }
  for (int off = 32; off; off >>= 1) v += __shfl_down(v, off);
  const float inv = rsqrtf(__shfl(v, 0) / (float)D + 1e-5f);
  float* orow = out + (size_t)wv * D;
  float a0 = 0.f, a1 = 0.f;
  for (int d = lane; d < D; d += 64) {
    const float o = (r[d] - mean) * inv * g[d] + b[d];
    orow[d] = o;
    if (outb) outb[(size_t)wv * D + d] = f2bf(o);
    if (gw) { a0 = fmaf(o, gw[2 * d], a0); a1 = fmaf(o, gw[2 * d + 1], a1); }
  }
  if (gw) {
    for (int off = 32; off; off >>= 1) { a0 += __shfl_down(a0, off); a1 += __shfl_down(a1, off); }
    if (lane == 0) {
      gamout[(size_t)wv * 2 + 0] = expf(a0 + gb[0]);
      gamout[(size_t)wv * 2 + 1] = expf(a1 + gb[1]);
    }
  }
}

// ---------------------------------------------------------------------------
// prep: bf16 adj_cls matrix (M_ x ACS per batch, zero-padded)
// ---------------------------------------------------------------------------
__global__ void adjc_k(const float* __restrict__ adj, unsigned short* __restrict__ adjc)
{
  const int n = blockIdx.x;   // 0..1024
  const int b = blockIdx.y;
  unsigned short* row = adjc + ((size_t)b * M_ + n) * ACS;
  const float* ar = (n >= 1) ? adj + ((size_t)b * NSEQ + (n - 1)) * NSEQ : nullptr;
  for (int m = threadIdx.x; m < ACS; m += 256) {
    float v = 0.f;
    if (n == 0) v = (m == 0) ? 1.f : 0.f;
    else if (m >= 1 && m <= NSEQ) v = ar[m - 1];
    row[m] = f2bf(v);
  }
}

// ---------------------------------------------------------------------------
// prep: Wt[n][k] = bf16(W[k][n])
// ---------------------------------------------------------------------------
__global__ void wtrans_k(const float* __restrict__ W, unsigned short* __restrict__ Wt,
                         int K, int N)
{
  __shared__ float t[32][33];
  const int k0 = blockIdx.x * 32, n0 = blockIdx.y * 32;
  const float* Wd = W + (size_t)blockIdx.z * K * N;
  unsigned short* Wtd = Wt + (size_t)blockIdx.z * K * N;
  for (int i = threadIdx.y; i < 32; i += 8)
    t[i][threadIdx.x] = Wd[(size_t)(k0 + i) * N + n0 + threadIdx.x];
  __syncthreads();
  for (int i = threadIdx.y; i < 32; i += 8)
    Wtd[(size_t)(n0 + i) * K + k0 + threadIdx.x] = f2bf(t[threadIdx.x][i]);
}

// ---------------------------------------------------------------------------
// per-layer: vt[b][h][d][m] = V = qkv[.., 2048 + h*128 + d]  (global transpose)
// grid (17, 8, 8), block 256. LDS 64x136 tile transpose.
// ---------------------------------------------------------------------------
__global__ __launch_bounds__(256) void vtrans_k(
    const unsigned short* __restrict__ qkv, unsigned short* __restrict__ vt)
{
  __shared__ unsigned short sT[64][136];
  const int mt = blockIdx.x, hh = blockIdx.y, b = blockIdx.z;
  const int tid = threadIdx.x;
  const int m0 = mt * 64;
#pragma unroll
  for (int l = 0; l < 4; ++l) {
    const int idx = l * 256 + tid;
    const int m = idx >> 4, c = idx & 15;
    const int gm = m0 + m;
    uint4 v = make_uint4(0u, 0u, 0u, 0u);
    if (gm < M_) v = *(const uint4*)(qkv + ((size_t)(b * M_ + gm)) * QKV3 + 2048 + hh * DIMC + c * 8);
    *(uint4*)&sT[m][c * 8] = v;
  }
  __syncthreads();
#pragma unroll
  for (int l = 0; l < 4; ++l) {
    const int idx = l * 256 + tid;
    const int d = idx >> 3, mc = idx & 7;
    unsigned short tmp[8];
#pragma unroll
    for (int j = 0; j < 8; ++j) tmp[j] = sT[mc * 8 + j][d];
    *(uint4*)(vt + (((size_t)(b * NHEADS + hh) * DIMC + d) * ACS) + m0 + mc * 8) = *(uint4*)tmp;
  }
}

// ---------------------------------------------------------------------------
// bf16 MFMA flash attention, Q-tile 128 (4 waves x 32 rows), K-tile 64.
// grid (8=heads, 9=qtile, 8=batch), block 256.
// V pre-transposed in global (vt). All LDS staging is vectorized b128.
// sVt/sPA use chunk-XOR swizzle: elem (row, m) at col ((m>>3)^(row&7 sel))*8|(m&7).
// ---------------------------------------------------------------------------
__global__ __launch_bounds__(256) void attn_mfma_k(
    const unsigned short* __restrict__ qkv, const float* __restrict__ gamma,
    const unsigned short* __restrict__ adjc, const unsigned short* __restrict__ vt,
    unsigned short* __restrict__ o)
{
  __shared__ unsigned short sK[64][136];    // keys row-major, pad 8
  __shared__ unsigned short sVt[128][72];   // transposed V, chunk-swizzled
  __shared__ unsigned short sPA[128][72];   // adj tile then P, chunk-swizzled

  const int hh = blockIdx.x, qt = blockIdx.y, b = blockIdx.z;
  const int tid = threadIdx.x;
  const int w = tid >> 6;
  const int lane = tid & 63;
  const int col = lane & 15;
  const int quad = lane >> 4;
  const int n0 = qt * 128;
  const int qbase = n0 + w * 32;
  const float scale = 0.088388347648318447f;  // 128^-0.5

  // Q fragments for 2 m-subtiles (registers, direct global)
  bf16x8 aQ[2][4];
#pragma unroll
  for (int ms = 0; ms < 2; ++ms) {
    const int qrow = min(qbase + ms * 16 + col, 1024);
    const unsigned short* qp = qkv + ((size_t)(b * M_ + qrow)) * QKV3 + hh * DIMC + quad * 8;
#pragma unroll
    for (int c = 0; c < 4; ++c) aQ[ms][c] = *(const bf16x8*)(qp + c * 32);
  }
  float g0[2][4], g1[2][4];
#pragma unroll
  for (int ms = 0; ms < 2; ++ms)
#pragma unroll
    for (int r = 0; r < 4; ++r) {
      const int nc = min(qbase + ms * 16 + quad * 4 + r, 1024);
      g0[ms][r] = gamma[(size_t)(b * M_ + nc) * 2 + 0] * scale;
      g1[ms][r] = gamma[(size_t)(b * M_ + nc) * 2 + 1];
    }

  float m_i[2][4], l_i[2][4];
  f32x4 Oacc[2][8];
#pragma unroll
  for (int ms = 0; ms < 2; ++ms) {
#pragma unroll
    for (int r = 0; r < 4; ++r) { m_i[ms][r] = -1e30f; l_i[ms][r] = 0.f; }
#pragma unroll
    for (int t = 0; t < 8; ++t) Oacc[ms][t] = (f32x4){0.f, 0.f, 0.f, 0.f};
  }

  const size_t vtbase = ((size_t)(b * NHEADS + hh)) * DIMC * ACS;

  for (int kt = 0; kt < 17; ++kt) {
    const int m0 = kt * 64;
    __syncthreads();
    // stage K rows (1024 uint4), Vt rows (1024), adj rows (1024) — all vector
#pragma unroll
    for (int l = 0; l < 4; ++l) {
      const int idx = l * 256 + tid;
      {
        const int m = idx >> 4, c = idx & 15;
        const int gm = m0 + m;
        uint4 kv = make_uint4(0u, 0u, 0u, 0u);
        if (gm < M_) kv = *(const uint4*)(qkv + ((size_t)(b * M_ + gm)) * QKV3 + 1024 + hh * DIMC + c * 8);
        *(uint4*)&sK[m][c * 8] = kv;
      }
      {
        const int d = idx >> 3, mc = idx & 7;
        const uint4 vv = *(const uint4*)(vt + vtbase + (size_t)d * ACS + m0 + mc * 8);
        const int swc = mc ^ ((d >> 3) & 7);
        *(uint4*)&sVt[d][swc * 8] = vv;
      }
      {
        const int rr = idx >> 3, c = idx & 7;
        const int nn = n0 + rr;
        uint4 av = make_uint4(0u, 0u, 0u, 0u);
        if (nn < M_) av = *(const uint4*)(adjc + ((size_t)b * M_ + nn) * ACS + m0 + c * 8);
        const int swc = c ^ (rr & 7);
        *(uint4*)&sPA[rr][swc * 8] = av;
      }
    }
    __syncthreads();

    // S = Q K^T : B-frags shared across both m-subtiles
    f32x4 Sacc[2][4];
#pragma unroll
    for (int ms = 0; ms < 2; ++ms)
#pragma unroll
      for (int t = 0; t < 4; ++t) Sacc[ms][t] = (f32x4){0.f, 0.f, 0.f, 0.f};
#pragma unroll
    for (int t = 0; t < 4; ++t) {
#pragma unroll
      for (int c = 0; c < 4; ++c) {
        const bf16x8 bK = *(const bf16x8*)&sK[t * 16 + col][c * 32 + quad * 8];
        Sacc[0][t] = __builtin_amdgcn_mfma_f32_16x16x32_bf16(aQ[0][c], bK, Sacc[0][t], 0, 0, 0);
        Sacc[1][t] = __builtin_amdgcn_mfma_f32_16x16x32_bf16(aQ[1][c], bK, Sacc[1][t], 0, 0, 0);
      }
    }

    // bias + mask (adj from swizzled sPA), then online softmax, then P write
#pragma unroll
    for (int ms = 0; ms < 2; ++ms) {
      float sv[4][4];
#pragma unroll
      for (int t = 0; t < 4; ++t) {
        const int m = m0 + t * 16 + col;
        const bool mv = (m < M_);
        const int chb = (t * 2 + (col >> 3));
#pragma unroll
        for (int r = 0; r < 4; ++r) {
          const int ql = w * 32 + ms * 16 + quad * 4 + r;
          const float av = bf2f(sPA[ql][((chb ^ (ql & 7)) * 8) + (col & 7)]);
          sv[t][r] = mv ? fmaf(g0[ms][r], Sacc[ms][t][r], g1[ms][r] * av) : -1e30f;
        }
      }
      float mnew[4];
#pragma unroll
      for (int r = 0; r < 4; ++r) {
        float mx = fmaxf(fmaxf(sv[0][r], sv[1][r]), fmaxf(sv[2][r], sv[3][r]));
        mx = fmaxf(mx, __shfl_xor(mx, 1));
        mx = fmaxf(mx, __shfl_xor(mx, 2));
        mx = fmaxf(mx, __shfl_xor(mx, 4));
        mx = fmaxf(mx, __shfl_xor(mx, 8));
        mnew[r] = fmaxf(m_i[ms][r], mx);
      }
      float ps[4] = {0.f, 0.f, 0.f, 0.f};
#pragma unroll
      for (int t = 0; t < 4; ++t) {
        const int chb = (t * 2 + (col >> 3));
#pragma unroll
        for (int r = 0; r < 4; ++r) {
          const float pv = __expf(sv[t][r] - mnew[r]);
          ps[r] += pv;
          const int ql = w * 32 + ms * 16 + quad * 4 + r;
          sPA[ql][((chb ^ (ql & 7)) * 8) + (col & 7)] = f2bf(pv);
        }
      }
#pragma unroll
      for (int r = 0; r < 4; ++r) {
        float s = ps[r];
        s += __shfl_xor(s, 1);
        s += __shfl_xor(s, 2);
        s += __shfl_xor(s, 4);
        s += __shfl_xor(s, 8);
        const float alpha = __expf(m_i[ms][r] - mnew[r]);
        l_i[ms][r] = l_i[ms][r] * alpha + s;
        m_i[ms][r] = mnew[r];
#pragma unroll
        for (int t = 0; t < 8; ++t) Oacc[ms][t][r] *= alpha;
      }
    }

    // O += P V : bV shared across both m-subtiles (own-wave P rows, no barrier)
#pragma unroll
    for (int ch = 0; ch < 2; ++ch) {
      const int r0a = w * 32 + col;
      const bf16x8 aP0 = *(const bf16x8*)&sPA[r0a][(((ch * 4 + quad) ^ (col & 7)) * 8)];
      const bf16x8 aP1 = *(const bf16x8*)&sPA[r0a + 16][(((ch * 4 + quad) ^ (col & 7)) * 8)];
#pragma unroll
      for (int t = 0; t < 8; ++t) {
        const int pc = (ch * 4 + quad) ^ ((t * 2 + (col >> 3)) & 7);
        const bf16x8 bV = *(const bf16x8*)&sVt[t * 16 + col][pc * 8];
        Oacc[0][t] = __builtin_amdgcn_mfma_f32_16x16x32_bf16(aP0, bV, Oacc[0][t], 0, 0, 0);
        Oacc[1][t] = __builtin_amdgcn_mfma_f32_16x16x32_bf16(aP1, bV, Oacc[1][t], 0, 0, 0);
      }
    }
  }

  // epilogue: bf16 output
#pragma unroll
  for (int ms = 0; ms < 2; ++ms)
#pragma unroll
    for (int r = 0; r < 4; ++r) {
      const int n = qbase + ms * 16 + quad * 4 + r;
      if (n < M_) {
        const float invl = 1.f / l_i[ms][r];
        unsigned short* orow = o + ((size_t)(b * M_ + n)) * (NHEADS * DIMC) + hh * DIMC + col;
#pragma unroll
        for (int t = 0; t < 8; ++t) orow[t * 16] = f2bf(Oacc[ms][t][r] * invl);
      }
    }
}

// ---------------------------------------------------------------------------
// small utility kernels
// ---------------------------------------------------------------------------
__global__ void concat_pe_k(const float* __restrict__ nf, const float* __restrict__ lp,
                            float* __restrict__ x35, int rows)
{
  const int idx = blockIdx.x * blockDim.x + threadIdx.x;
  if (idx >= rows * 35) return;
  const int r = idx / 35, c = idx - r * 35;
  x35[idx] = (c < 3) ? nf[(size_t)r * 3 + c] : lp[(size_t)r * 32 + (c - 3)];
}

__global__ void fill_cls_k(const float* __restrict__ cls, float* __restrict__ x)
{
  x[(size_t)blockIdx.x * M_ * DIMC + threadIdx.x] = cls[threadIdx.x];
}

__global__ void extract_cls_k(const float* __restrict__ x, float* __restrict__ c0)
{
  c0[(size_t)blockIdx.x * DIMC + threadIdx.x] = x[(size_t)blockIdx.x * M_ * DIMC + threadIdx.x];
}

// ---------------------------------------------------------------------------
extern "C" void kernel_launch(void* const* d_in, const int* in_sizes, int n_in,
                              void* d_out, int out_size, void* d_ws, size_t ws_size,
                              hipStream_t stream)
{
  (void)in_sizes; (void)n_in; (void)out_size; (void)ws_size;
  const float* node_feat = (const float*)d_in[0];
  const float* adj       = (const float*)d_in[1];
  const float* lapl      = (const float*)d_in[2];
  const float* cls_token = (const float*)d_in[3];
  const float* pe_w1 = (const float*)d_in[4];
  const float* pe_b1 = (const float*)d_in[5];
  const float* pe_w2 = (const float*)d_in[6];
  const float* pe_b2 = (const float*)d_in[7];
  const float* pe_w3 = (const float*)d_in[8];
  const float* pe_b3 = (const float*)d_in[9];
  const float* pe_lng = (const float*)d_in[10];
  const float* pe_lnb = (const float*)d_in[11];
  const float* pe_w4 = (const float*)d_in[12];
  const float* pe_b4 = (const float*)d_in[13];
  const float* blk_ln1_g = (const float*)d_in[14];
  const float* blk_ln1_b = (const float*)d_in[15];
  const float* blk_qkv_w = (const float*)d_in[16];
  const float* blk_proj_w = (const float*)d_in[17];
  const float* blk_proj_b = (const float*)d_in[18];
  const float* blk_gamma_w = (const float*)d_in[19];
  const float* blk_gamma_b = (const float*)d_in[20];
  const float* blk_ln2_g = (const float*)d_in[21];
  const float* blk_ln2_b = (const float*)d_in[22];
  const float* blk_mlp_w1 = (const float*)d_in[23];
  const float* blk_mlp_b1 = (const float*)d_in[24];
  const float* blk_mlp_w2 = (const float*)d_in[25];
  const float* blk_mlp_b2 = (const float*)d_in[26];
  const float* head_lng = (const float*)d_in[27];
  const float* head_lnb = (const float*)d_in[28];
  const float* head_w = (const float*)d_in[29];
  const float* head_b = (const float*)d_in[30];
  const float* proj_w1 = (const float*)d_in[31];
  const float* proj_b1 = (const float*)d_in[32];
  const float* proj_w2 = (const float*)d_in[33];
  const float* proj_b2 = (const float*)d_in[34];
  const float* proj_w3 = (const float*)d_in[35];
  const float* proj_b3 = (const float*)d_in[36];
  const float* proj_lng = (const float*)d_in[37];
  const float* proj_lnb = (const float*)d_in[38];
  const float* proj_w4 = (const float*)d_in[39];
  const float* proj_b4 = (const float*)d_in[40];

  // ---- workspace layout ----
  float* ws   = (float*)d_ws;
  float* x    = ws;                        // 1,049,600 f
  float* h    = x + 1049600;               // 1,049,600 f
  float* gam  = h + 1049600;               // 16,400 f
  float* obuf = gam + 16400;               // 5,248,000 f region
  unsigned short* obufb = (unsigned short*)obuf;             // 8200*1024 bf16
  unsigned short* hidb  = (unsigned short*)(obuf + 4198400); // 8200*256 bf16
  float* x35 = obuf;                        // PE scratch (pre-layers)
  float* xa  = obuf + 300000;
  float* xb  = obuf + 900000;
  float* sm  = obuf + 5248000;             // 8,192 f
  unsigned short* hb   = (unsigned short*)(sm + 8192);       // 8200*128 bf16
  unsigned short* qkv  = hb + 1049600;     // 25,190,400 us
  unsigned short* adjc = qkv + 25190400;   // 8,921,600 us
  unsigned short* vt   = adjc + 8921600;   // 8*8*128*1088 = 8,912,896 us
  unsigned short* qkvWt = vt + 8912896;    // 5*393216
  unsigned short* projWt = qkvWt + 5 * 393216;
  unsigned short* mlp1Wt = projWt + 5 * 131072;
  unsigned short* mlp2Wt = mlp1Wt + 5 * 32768;
  float* s0 = sm, *s1 = sm + 1024, *s2 = sm + 2048, *s3 = sm + 3072;

  float* out_c = (float*)d_out;            // (8,128)
  float* out_p = out_c + NB * DIMC;        // (8,1000)

  // ---- prep ----
  adjc_k<<<dim3(M_, NB), 256, 0, stream>>>(adj, adjc);
  wtrans_k<<<dim3(4, 96, 5), dim3(32, 8), 0, stream>>>(blk_qkv_w, qkvWt, 128, 3072);
  wtrans_k<<<dim3(32, 4, 5), dim3(32, 8), 0, stream>>>(blk_proj_w, projWt, 1024, 128);
  wtrans_k<<<dim3(4, 8, 5), dim3(32, 8), 0, stream>>>(blk_mlp_w1, mlp1Wt, 128, 256);
  wtrans_k<<<dim3(8, 4, 5), dim3(32, 8), 0, stream>>>(blk_mlp_w2, mlp2Wt, 256, 128);

  // ---- PE encoder (fp32) ----
  concat_pe_k<<<(PEROWS * 35 + 255) / 256, 256, 0, stream>>>(node_feat, lapl, x35, PEROWS);
  rowgemm_k<16><<<dim3(512, 1), 128, 16 * 35 * 4, stream>>>(x35, pe_w1, pe_b1, nullptr, xa, PEROWS, 35, 70, 1, 0);
  rowgemm_k<16><<<dim3(512, 1), 128, 16 * 70 * 4, stream>>>(xa, pe_w2, pe_b2, nullptr, xb, PEROWS, 70, 70, 1, 0);
  rowgemm_k<16><<<dim3(512, 1), 128, 16 * 70 * 4, stream>>>(xb, pe_w3, pe_b3, nullptr, xa, PEROWS, 70, 70, 1, 0);
  ln_rows_k<<<(PEROWS * 64 + 255) / 256, 256, 0, stream>>>(xa, xb, nullptr, pe_lng, pe_lnb, nullptr, nullptr, nullptr, PEROWS, 70);
  rowgemm_k<16><<<dim3(512, 1), 128, 16 * 70 * 4, stream>>>(xb, pe_w4, pe_b4, nullptr, x, PEROWS, 70, DIMC, 0, 1);
  fill_cls_k<<<NB, DIMC, 0, stream>>>(cls_token, x);

  // ---- transformer layers ----
  const int lnGrid = (ROWS * 64 + 255) / 256;  // 2050
  for (int i = 0; i < 5; ++i) {
    const float* ln1g = blk_ln1_g + i * DIMC;
    const float* ln1b = blk_ln1_b + i * DIMC;
    const float* pb   = blk_proj_b + i * DIMC;
    const float* gw   = blk_gamma_w + (size_t)i * DIMC * 2;
    const float* gb   = blk_gamma_b + i * 2;
    const float* ln2g = blk_ln2_g + i * DIMC;
    const float* ln2b = blk_ln2_b + i * DIMC;
    const float* mb1  = blk_mlp_b1 + i * 256;
    const float* mb2  = blk_mlp_b2 + i * DIMC;
    const unsigned short* qw = qkvWt + (size_t)i * 393216;
    const unsigned short* pw = projWt + (size_t)i * 131072;
    const unsigned short* m1w = mlp1Wt + (size_t)i * 32768;
    const unsigned short* m2w = mlp2Wt + (size_t)i * 32768;

    ln_rows_k<<<lnGrid, 256, 0, stream>>>(x, h, hb, ln1g, ln1b, gw, gb, gam, ROWS, DIMC);
    mgemm_k<0, 1, 0><<<dim3(129, 48), 256, 0, stream>>>(hb, qw, nullptr, nullptr, qkv, ROWS, 128, 3072);
    vtrans_k<<<dim3(17, NHEADS, NB), 256, 0, stream>>>(qkv, vt);
    attn_mfma_k<<<dim3(NHEADS, 9, NB), 256, 0, stream>>>(qkv, gam, adjc, vt, obufb);
    mgemm_k<0, 0, 1><<<dim3(129, 2), 256, 0, stream>>>(obufb, pw, pb, h, x, ROWS, 1024, 128);
    ln_rows_k<<<lnGrid, 256, 0, stream>>>(x, h, hb, ln2g, ln2b, nullptr, nullptr, nullptr, ROWS, DIMC);
    mgemm_k<1, 1, 0><<<dim3(129, 4), 256, 0, stream>>>(hb, m1w, mb1, nullptr, hidb, ROWS, 128, 256);
    mgemm_k<0, 0, 1><<<dim3(129, 2), 256, 0, stream>>>(hidb, m2w, mb2, h, x, ROWS, 256, 128);
  }

  // ---- head (fp32) ----
  extract_cls_k<<<NB, DIMC, 0, stream>>>(x, s0);
  ln_rows_k<<<2, 256, 0, stream>>>(s0, s1, nullptr, head_lng, head_lnb, nullptr, nullptr, nullptr, NB, DIMC);
  rowgemm_k<8><<<dim3(1, 1), 128, 8 * 128 * 4, stream>>>(s1, head_w, head_b, nullptr, out_c, NB, DIMC, DIMC, 0, 0);
  rowgemm_k<8><<<dim3(1, 1), 128, 8 * 128 * 4, stream>>>(out_c, proj_w1, proj_b1, nullptr, s2, NB, DIMC, DIMC, 1, 0);
  rowgemm_k<8><<<dim3(1, 1), 128, 8 * 128 * 4, stream>>>(s2, proj_w2, proj_b2, nullptr, s3, NB, DIMC, DIMC, 1, 0);
  rowgemm_k<8><<<dim3(1, 1), 128, 8 * 128 * 4, stream>>>(s3, proj_w3, proj_b3, nullptr, s2, NB, DIMC, DIMC, 1, 0);
  ln_rows_k<<<2, 256, 0, stream>>>(s2, s3, nullptr, proj_lng, proj_lnb, nullptr, nullptr, nullptr, NB, DIMC);
  rowgemm_k<8><<<dim3(1, 4), 256, 8 * 128 * 4, stream>>>(s3, proj_w4, proj_b4, nullptr, out_p, NB, DIMC, 1000, 0, 0);
}

// Round 6
// 1866.860 us; speedup vs baseline: 1.3343x; 1.3343x over previous
//
#include <hip/hip_runtime.h>
#include <hip/hip_bf16.h>
#include <math.h>

// Problem constants
#define NB 8
#define NSEQ 1024
#define M_ 1025                 // NSEQ + 1 (cls)
#define ROWS (NB * M_)          // 8200
#define DIMC 128
#define NHEADS 8
#define QKV3 3072               // 3*8*128
#define PEROWS (NB * NSEQ)      // 8192
#define ACS 1088                // adj_cls / vt padded column stride

typedef __attribute__((ext_vector_type(8))) short bf16x8;
typedef __attribute__((ext_vector_type(4))) float f32x4;

__device__ __forceinline__ float gelu_f(float x) {
  return 0.5f * x * (1.f + erff(x * 0.70710678118654752440f));
}

__device__ __forceinline__ unsigned short f2bf(float f) {
  __hip_bfloat16 h = __float2bfloat16(f);
  return *reinterpret_cast<unsigned short*>(&h);
}

__device__ __forceinline__ float bf2f(unsigned short u) {
  union { unsigned int i; float f; } c;
  c.i = ((unsigned int)u) << 16;
  return c.f;
}

// ---------------------------------------------------------------------------
// fp32 row-tiled GEMM (PE encoder + head only)
// ---------------------------------------------------------------------------
template<int TR>
__global__ __launch_bounds__(256) void rowgemm_k(
    const float* __restrict__ in, const float* __restrict__ W,
    const float* __restrict__ bias, const float* __restrict__ res,
    float* __restrict__ out, int rows, int K, int Nout, int act, int remap)
{
  extern __shared__ float s_in[];
  const int tid = threadIdx.x;
  const int r0 = blockIdx.x * TR;
  const int tot = TR * K;
  for (int idx = tid; idx < tot; idx += blockDim.x) {
    int r = idx / K;
    int k = idx - r * K;
    int gr = r0 + r;
    s_in[idx] = (gr < rows) ? in[(size_t)gr * K + k] : 0.f;
  }
  __syncthreads();
  const int j = blockIdx.y * blockDim.x + tid;
  if (j >= Nout) return;
  float acc[TR];
  const float bv = bias ? bias[j] : 0.f;
#pragma unroll
  for (int r = 0; r < TR; ++r) acc[r] = bv;
  for (int k = 0; k < K; ++k) {
    const float w = W[(size_t)k * Nout + j];
#pragma unroll
    for (int r = 0; r < TR; ++r) acc[r] = fmaf(s_in[r * K + k], w, acc[r]);
  }
  for (int r = 0; r < TR; ++r) {
    const int gr = r0 + r;
    if (gr >= rows) break;
    float v = acc[r];
    if (act == 1) v = gelu_f(v);
    if (res) v += res[(size_t)gr * Nout + j];
    const size_t orow = remap ? (size_t)(gr + gr / 1024 + 1) : (size_t)gr;
    out[orow * (size_t)Nout + j] = v;
  }
}

// ---------------------------------------------------------------------------
// bf16 MFMA GEMM: out = [act]( Xb @ Wt^T + bias ) [+ res]
// ---------------------------------------------------------------------------
template<int ACT, int OBF, int RES>
__global__ __launch_bounds__(256) void mgemm_k(
    const unsigned short* __restrict__ Xb, const unsigned short* __restrict__ Wt,
    const float* __restrict__ bias, const float* __restrict__ res,
    void* __restrict__ outp, int rows, int K, int N)
{
  __shared__ unsigned short sX[64][72];
  __shared__ unsigned short sW[64][72];
  const int tid = threadIdx.x;
  const int w = tid >> 6, lane = tid & 63;
  const int col = lane & 15, quad = lane >> 4;
  const int r0 = blockIdx.x * 64, n0 = blockIdx.y * 64;
  const int lr = tid >> 2, lc = tid & 3;
  const int xrow = min(r0 + lr, rows - 1);
  const unsigned short* xsrc = Xb + (size_t)xrow * K + lc * 8;
  const unsigned short* wsrc = Wt + (size_t)(n0 + lr) * K + lc * 8;

  f32x4 acc[4];
#pragma unroll
  for (int t = 0; t < 4; ++t) acc[t] = (f32x4){0.f, 0.f, 0.f, 0.f};

  for (int k0 = 0; k0 < K; k0 += 64) {
    __syncthreads();
    *(uint4*)&sX[lr][lc * 8]      = *(const uint4*)(xsrc + k0);
    *(uint4*)&sX[lr][lc * 8 + 32] = *(const uint4*)(xsrc + k0 + 32);
    *(uint4*)&sW[lr][lc * 8]      = *(const uint4*)(wsrc + k0);
    *(uint4*)&sW[lr][lc * 8 + 32] = *(const uint4*)(wsrc + k0 + 32);
    __syncthreads();
    const bf16x8 aX0 = *(const bf16x8*)&sX[w * 16 + col][quad * 8];
    const bf16x8 aX1 = *(const bf16x8*)&sX[w * 16 + col][32 + quad * 8];
#pragma unroll
    for (int t = 0; t < 4; ++t) {
      const bf16x8 bW0 = *(const bf16x8*)&sW[t * 16 + col][quad * 8];
      const bf16x8 bW1 = *(const bf16x8*)&sW[t * 16 + col][32 + quad * 8];
      acc[t] = __builtin_amdgcn_mfma_f32_16x16x32_bf16(aX0, bW0, acc[t], 0, 0, 0);
      acc[t] = __builtin_amdgcn_mfma_f32_16x16x32_bf16(aX1, bW1, acc[t], 0, 0, 0);
    }
  }
  const int gr_base = r0 + w * 16 + quad * 4;
#pragma unroll
  for (int t = 0; t < 4; ++t) {
    const int n = n0 + t * 16 + col;
    const float bv = bias ? bias[n] : 0.f;
#pragma unroll
    for (int r = 0; r < 4; ++r) {
      const int gr = gr_base + r;
      if (gr < rows) {
        float v = acc[t][r] + bv;
        if (ACT) v = gelu_f(v);
        if (RES) v += res[(size_t)gr * N + n];
        if (OBF) ((unsigned short*)outp)[(size_t)gr * N + n] = f2bf(v);
        else     ((float*)outp)[(size_t)gr * N + n] = v;
      }
    }
  }
}

// ---------------------------------------------------------------------------
// Wave-per-row LayerNorm; optional bf16 shadow out; optional fused gamma
// ---------------------------------------------------------------------------
__global__ __launch_bounds__(256) void ln_rows_k(
    const float* __restrict__ in, float* __restrict__ out,
    unsigned short* __restrict__ outb,
    const float* __restrict__ g, const float* __restrict__ b,
    const float* __restrict__ gw, const float* __restrict__ gb,
    float* __restrict__ gamout, int rows, int D)
{
  const int wv = (blockIdx.x * blockDim.x + threadIdx.x) >> 6;
  const int lane = threadIdx.x & 63;
  if (wv >= rows) return;
  const float* r = in + (size_t)wv * D;
  float s = 0.f;
  for (int d = lane; d < D; d += 64) s += r[d];
  for (int off = 32; off; off >>= 1) s += __shfl_down(s, off);
  const float mean = __shfl(s, 0) / (float)D;
  float v = 0.f;
  for (int d = lane; d < D; d += 64) { float t = r[d] - mean; v += t * t; }
  for (int off = 32; off; off >>= 1) v += __shfl_down(v, off);
  const float inv = rsqrtf(__shfl(v, 0) / (float)D + 1e-5f);
  float* orow = out + (size_t)wv * D;
  float a0 = 0.f, a1 = 0.f;
  for (int d = lane; d < D; d += 64) {
    const float o = (r[d] - mean) * inv * g[d] + b[d];
    orow[d] = o;
    if (outb) outb[(size_t)wv * D + d] = f2bf(o);
    if (gw) { a0 = fmaf(o, gw[2 * d], a0); a1 = fmaf(o, gw[2 * d + 1], a1); }
  }
  if (gw) {
    for (int off = 32; off; off >>= 1) { a0 += __shfl_down(a0, off); a1 += __shfl_down(a1, off); }
    if (lane == 0) {
      gamout[(size_t)wv * 2 + 0] = expf(a0 + gb[0]);
      gamout[(size_t)wv * 2 + 1] = expf(a1 + gb[1]);
    }
  }
}

// ---------------------------------------------------------------------------
// prep: bf16 adj_cls matrix (M_ x ACS per batch, zero-padded)
// ---------------------------------------------------------------------------
__global__ void adjc_k(const float* __restrict__ adj, unsigned short* __restrict__ adjc)
{
  const int n = blockIdx.x;   // 0..1024
  const int b = blockIdx.y;
  unsigned short* row = adjc + ((size_t)b * M_ + n) * ACS;
  const float* ar = (n >= 1) ? adj + ((size_t)b * NSEQ + (n - 1)) * NSEQ : nullptr;
  for (int m = threadIdx.x; m < ACS; m += 256) {
    float v = 0.f;
    if (n == 0) v = (m == 0) ? 1.f : 0.f;
    else if (m >= 1 && m <= NSEQ) v = ar[m - 1];
    row[m] = f2bf(v);
  }
}

// ---------------------------------------------------------------------------
// prep: Wt[n][k] = bf16(W[k][n])
// ---------------------------------------------------------------------------
__global__ void wtrans_k(const float* __restrict__ W, unsigned short* __restrict__ Wt,
                         int K, int N)
{
  __shared__ float t[32][33];
  const int k0 = blockIdx.x * 32, n0 = blockIdx.y * 32;
  const float* Wd = W + (size_t)blockIdx.z * K * N;
  unsigned short* Wtd = Wt + (size_t)blockIdx.z * K * N;
  for (int i = threadIdx.y; i < 32; i += 8)
    t[i][threadIdx.x] = Wd[(size_t)(k0 + i) * N + n0 + threadIdx.x];
  __syncthreads();
  for (int i = threadIdx.y; i < 32; i += 8)
    Wtd[(size_t)(n0 + i) * K + k0 + threadIdx.x] = f2bf(t[threadIdx.x][i]);
}

// ---------------------------------------------------------------------------
// per-layer: vt[b][h][d][m] = V = qkv[.., 2048 + h*128 + d]  (global transpose)
// grid (17, 8, 8), block 256. LDS 64x136 tile transpose.
// ---------------------------------------------------------------------------
__global__ __launch_bounds__(256) void vtrans_k(
    const unsigned short* __restrict__ qkv, unsigned short* __restrict__ vt)
{
  __shared__ unsigned short sT[64][136];
  const int mt = blockIdx.x, hh = blockIdx.y, b = blockIdx.z;
  const int tid = threadIdx.x;
  const int m0 = mt * 64;
#pragma unroll
  for (int l = 0; l < 4; ++l) {
    const int idx = l * 256 + tid;
    const int m = idx >> 4, c = idx & 15;
    const int gm = m0 + m;
    uint4 v = make_uint4(0u, 0u, 0u, 0u);
    if (gm < M_) v = *(const uint4*)(qkv + ((size_t)(b * M_ + gm)) * QKV3 + 2048 + hh * DIMC + c * 8);
    *(uint4*)&sT[m][c * 8] = v;
  }
  __syncthreads();
#pragma unroll
  for (int l = 0; l < 4; ++l) {
    const int idx = l * 256 + tid;
    const int d = idx >> 3, mc = idx & 7;
    unsigned short tmp[8];
#pragma unroll
    for (int j = 0; j < 8; ++j) tmp[j] = sT[mc * 8 + j][d];
    *(uint4*)(vt + (((size_t)(b * NHEADS + hh) * DIMC + d) * ACS) + m0 + mc * 8) = *(uint4*)tmp;
  }
}

// ---------------------------------------------------------------------------
// bf16 MFMA flash attention, Q-tile 64 (4 waves x 16 rows), K-tile 64.
// grid (8=heads, 17=qtile, 8=batch), block 256.
// V pre-transposed in global (vt) -> all LDS staging is vectorized b128.
// sVt chunk-XOR swizzle: (d, m-chunk mc) stored at col (mc ^ ((d>>3)&7)).
// sPA chunk-XOR swizzle: (row ql, chunk c) stored at col (c ^ (ql&7)).
// ---------------------------------------------------------------------------
__global__ __launch_bounds__(256) void attn_mfma_k(
    const unsigned short* __restrict__ qkv, const float* __restrict__ gamma,
    const unsigned short* __restrict__ adjc, const unsigned short* __restrict__ vt,
    unsigned short* __restrict__ o)
{
  __shared__ unsigned short sK[64][136];    // keys row-major, pad 8
  __shared__ unsigned short sVt[128][72];   // transposed V, chunk-swizzled
  __shared__ unsigned short sPA[64][72];    // adj tile then P, chunk-swizzled

  const int hh = blockIdx.x, qt = blockIdx.y, b = blockIdx.z;
  const int tid = threadIdx.x;
  const int w = tid >> 6;
  const int lane = tid & 63;
  const int col = lane & 15;
  const int quad = lane >> 4;
  const int n0 = qt * 64;
  const int qbase = n0 + w * 16;
  const float scale = 0.088388347648318447f;  // 128^-0.5

  // Q fragments (registers, direct global)
  bf16x8 aQ[4];
  {
    const int qrow = min(qbase + col, 1024);
    const unsigned short* qp = qkv + ((size_t)(b * M_ + qrow)) * QKV3 + hh * DIMC + quad * 8;
#pragma unroll
    for (int c = 0; c < 4; ++c) aQ[c] = *(const bf16x8*)(qp + c * 32);
  }
  float g0[4], g1[4];
#pragma unroll
  for (int r = 0; r < 4; ++r) {
    const int nc = min(qbase + quad * 4 + r, 1024);
    g0[r] = gamma[(size_t)(b * M_ + nc) * 2 + 0] * scale;
    g1[r] = gamma[(size_t)(b * M_ + nc) * 2 + 1];
  }

  float m_i[4], l_i[4];
  f32x4 Oacc[8];
#pragma unroll
  for (int r = 0; r < 4; ++r) { m_i[r] = -1e30f; l_i[r] = 0.f; }
#pragma unroll
  for (int t = 0; t < 8; ++t) Oacc[t] = (f32x4){0.f, 0.f, 0.f, 0.f};

  const size_t vtbase = ((size_t)(b * NHEADS + hh)) * DIMC * ACS;

  for (int kt = 0; kt < 17; ++kt) {
    const int m0 = kt * 64;
    __syncthreads();
    // stage K rows (1024 uint4), Vt rows (1024), adj rows (512) — all vector
#pragma unroll
    for (int l = 0; l < 4; ++l) {
      const int idx = l * 256 + tid;
      {
        const int m = idx >> 4, c = idx & 15;
        const int gm = m0 + m;
        uint4 kv = make_uint4(0u, 0u, 0u, 0u);
        if (gm < M_) kv = *(const uint4*)(qkv + ((size_t)(b * M_ + gm)) * QKV3 + 1024 + hh * DIMC + c * 8);
        *(uint4*)&sK[m][c * 8] = kv;
      }
      {
        const int d = idx >> 3, mc = idx & 7;
        const uint4 vv = *(const uint4*)(vt + vtbase + (size_t)d * ACS + m0 + mc * 8);
        const int swc = mc ^ ((d >> 3) & 7);
        *(uint4*)&sVt[d][swc * 8] = vv;
      }
      if (l < 2) {
        const int rr = idx >> 3, c = idx & 7;   // idx < 512 covers 64 rows x 8 chunks
        const int nn = n0 + rr;
        uint4 av = make_uint4(0u, 0u, 0u, 0u);
        if (nn < M_) av = *(const uint4*)(adjc + ((size_t)b * M_ + nn) * ACS + m0 + c * 8);
        const int swc = c ^ (rr & 7);
        *(uint4*)&sPA[rr][swc * 8] = av;
      }
    }
    __syncthreads();

    // S = Q K^T
    f32x4 Sacc[4];
#pragma unroll
    for (int t = 0; t < 4; ++t) Sacc[t] = (f32x4){0.f, 0.f, 0.f, 0.f};
#pragma unroll
    for (int t = 0; t < 4; ++t) {
#pragma unroll
      for (int c = 0; c < 4; ++c) {
        const bf16x8 bK = *(const bf16x8*)&sK[t * 16 + col][c * 32 + quad * 8];
        Sacc[t] = __builtin_amdgcn_mfma_f32_16x16x32_bf16(aQ[c], bK, Sacc[t], 0, 0, 0);
      }
    }

    // bias + mask (adj from swizzled sPA)
    float sv[4][4];
#pragma unroll
    for (int t = 0; t < 4; ++t) {
      const int m = m0 + t * 16 + col;
      const bool mv = (m < M_);
      const int chb = t * 2 + (col >> 3);
#pragma unroll
      for (int r = 0; r < 4; ++r) {
        const int ql = w * 16 + quad * 4 + r;
        const float av = bf2f(sPA[ql][((chb ^ (ql & 7)) * 8) + (col & 7)]);
        sv[t][r] = mv ? fmaf(g0[r], Sacc[t][r], g1[r] * av) : -1e30f;
      }
    }

    // online softmax
    float mnew[4];
#pragma unroll
    for (int r = 0; r < 4; ++r) {
      float mx = fmaxf(fmaxf(sv[0][r], sv[1][r]), fmaxf(sv[2][r], sv[3][r]));
      mx = fmaxf(mx, __shfl_xor(mx, 1));
      mx = fmaxf(mx, __shfl_xor(mx, 2));
      mx = fmaxf(mx, __shfl_xor(mx, 4));
      mx = fmaxf(mx, __shfl_xor(mx, 8));
      mnew[r] = fmaxf(m_i[r], mx);
    }
    float ps[4] = {0.f, 0.f, 0.f, 0.f};
#pragma unroll
    for (int t = 0; t < 4; ++t) {
      const int chb = t * 2 + (col >> 3);
#pragma unroll
      for (int r = 0; r < 4; ++r) {
        const float pv = __expf(sv[t][r] - mnew[r]);
        ps[r] += pv;
        const int ql = w * 16 + quad * 4 + r;
        sPA[ql][((chb ^ (ql & 7)) * 8) + (col & 7)] = f2bf(pv);
      }
    }
#pragma unroll
    for (int r = 0; r < 4; ++r) {
      float s = ps[r];
      s += __shfl_xor(s, 1);
      s += __shfl_xor(s, 2);
      s += __shfl_xor(s, 4);
      s += __shfl_xor(s, 8);
      const float alpha = __expf(m_i[r] - mnew[r]);
      l_i[r] = l_i[r] * alpha + s;
      m_i[r] = mnew[r];
#pragma unroll
      for (int t = 0; t < 8; ++t) Oacc[t][r] *= alpha;
    }

    // O += P V (own-wave P rows; swizzled reads)
#pragma unroll
    for (int ch = 0; ch < 2; ++ch) {
      const int r0a = w * 16 + col;
      const bf16x8 aP = *(const bf16x8*)&sPA[r0a][(((ch * 4 + quad) ^ (col & 7)) * 8)];
#pragma unroll
      for (int t = 0; t < 8; ++t) {
        const int pc = (ch * 4 + quad) ^ ((t * 2 + (col >> 3)) & 7);
        const bf16x8 bV = *(const bf16x8*)&sVt[t * 16 + col][pc * 8];
        Oacc[t] = __builtin_amdgcn_mfma_f32_16x16x32_bf16(aP, bV, Oacc[t], 0, 0, 0);
      }
    }
  }

  // epilogue: bf16 output
#pragma unroll
  for (int r = 0; r < 4; ++r) {
    const int n = qbase + quad * 4 + r;
    if (n < M_) {
      const float invl = 1.f / l_i[r];
      unsigned short* orow = o + ((size_t)(b * M_ + n)) * (NHEADS * DIMC) + hh * DIMC + col;
#pragma unroll
      for (int t = 0; t < 8; ++t) orow[t * 16] = f2bf(Oacc[t][r] * invl);
    }
  }
}

// ---------------------------------------------------------------------------
// small utility kernels
// ---------------------------------------------------------------------------
__global__ void concat_pe_k(const float* __restrict__ nf, const float* __restrict__ lp,
                            float* __restrict__ x35, int rows)
{
  const int idx = blockIdx.x * blockDim.x + threadIdx.x;
  if (idx >= rows * 35) return;
  const int r = idx / 35, c = idx - r * 35;
  x35[idx] = (c < 3) ? nf[(size_t)r * 3 + c] : lp[(size_t)r * 32 + (c - 3)];
}

__global__ void fill_cls_k(const float* __restrict__ cls, float* __restrict__ x)
{
  x[(size_t)blockIdx.x * M_ * DIMC + threadIdx.x] = cls[threadIdx.x];
}

__global__ void extract_cls_k(const float* __restrict__ x, float* __restrict__ c0)
{
  c0[(size_t)blockIdx.x * DIMC + threadIdx.x] = x[(size_t)blockIdx.x * M_ * DIMC + threadIdx.x];
}

// ---------------------------------------------------------------------------
extern "C" void kernel_launch(void* const* d_in, const int* in_sizes, int n_in,
                              void* d_out, int out_size, void* d_ws, size_t ws_size,
                              hipStream_t stream)
{
  (void)in_sizes; (void)n_in; (void)out_size; (void)ws_size;
  const float* node_feat = (const float*)d_in[0];
  const float* adj       = (const float*)d_in[1];
  const float* lapl      = (const float*)d_in[2];
  const float* cls_token = (const float*)d_in[3];
  const float* pe_w1 = (const float*)d_in[4];
  const float* pe_b1 = (const float*)d_in[5];
  const float* pe_w2 = (const float*)d_in[6];
  const float* pe_b2 = (const float*)d_in[7];
  const float* pe_w3 = (const float*)d_in[8];
  const float* pe_b3 = (const float*)d_in[9];
  const float* pe_lng = (const float*)d_in[10];
  const float* pe_lnb = (const float*)d_in[11];
  const float* pe_w4 = (const float*)d_in[12];
  const float* pe_b4 = (const float*)d_in[13];
  const float* blk_ln1_g = (const float*)d_in[14];
  const float* blk_ln1_b = (const float*)d_in[15];
  const float* blk_qkv_w = (const float*)d_in[16];
  const float* blk_proj_w = (const float*)d_in[17];
  const float* blk_proj_b = (const float*)d_in[18];
  const float* blk_gamma_w = (const float*)d_in[19];
  const float* blk_gamma_b = (const float*)d_in[20];
  const float* blk_ln2_g = (const float*)d_in[21];
  const float* blk_ln2_b = (const float*)d_in[22];
  const float* blk_mlp_w1 = (const float*)d_in[23];
  const float* blk_mlp_b1 = (const float*)d_in[24];
  const float* blk_mlp_w2 = (const float*)d_in[25];
  const float* blk_mlp_b2 = (const float*)d_in[26];
  const float* head_lng = (const float*)d_in[27];
  const float* head_lnb = (const float*)d_in[28];
  const float* head_w = (const float*)d_in[29];
  const float* head_b = (const float*)d_in[30];
  const float* proj_w1 = (const float*)d_in[31];
  const float* proj_b1 = (const float*)d_in[32];
  const float* proj_w2 = (const float*)d_in[33];
  const float* proj_b2 = (const float*)d_in[34];
  const float* proj_w3 = (const float*)d_in[35];
  const float* proj_b3 = (const float*)d_in[36];
  const float* proj_lng = (const float*)d_in[37];
  const float* proj_lnb = (const float*)d_in[38];
  const float* proj_w4 = (const float*)d_in[39];
  const float* proj_b4 = (const float*)d_in[40];

  // ---- workspace layout ----
  float* ws   = (float*)d_ws;
  float* x    = ws;                        // 1,049,600 f
  float* h    = x + 1049600;               // 1,049,600 f
  float* gam  = h + 1049600;               // 16,400 f
  float* obuf = gam + 16400;               // 5,248,000 f region
  unsigned short* obufb = (unsigned short*)obuf;             // 8200*1024 bf16
  unsigned short* hidb  = (unsigned short*)(obuf + 4198400); // 8200*256 bf16
  float* x35 = obuf;                        // PE scratch (pre-layers)
  float* xa  = obuf + 300000;
  float* xb  = obuf + 900000;
  float* sm  = obuf + 5248000;             // 8,192 f
  unsigned short* hb   = (unsigned short*)(sm + 8192);       // 8200*128 bf16
  unsigned short* qkv  = hb + 1049600;     // 25,190,400 us
  unsigned short* adjc = qkv + 25190400;   // 8,921,600 us
  unsigned short* vt   = adjc + 8921600;   // 8*8*128*1088 = 8,912,896 us
  unsigned short* qkvWt = vt + 8912896;    // 5*393216
  unsigned short* projWt = qkvWt + 5 * 393216;
  unsigned short* mlp1Wt = projWt + 5 * 131072;
  unsigned short* mlp2Wt = mlp1Wt + 5 * 32768;
  float* s0 = sm, *s1 = sm + 1024, *s2 = sm + 2048, *s3 = sm + 3072;

  float* out_c = (float*)d_out;            // (8,128)
  float* out_p = out_c + NB * DIMC;        // (8,1000)

  // ---- prep ----
  adjc_k<<<dim3(M_, NB), 256, 0, stream>>>(adj, adjc);
  wtrans_k<<<dim3(4, 96, 5), dim3(32, 8), 0, stream>>>(blk_qkv_w, qkvWt, 128, 3072);
  wtrans_k<<<dim3(32, 4, 5), dim3(32, 8), 0, stream>>>(blk_proj_w, projWt, 1024, 128);
  wtrans_k<<<dim3(4, 8, 5), dim3(32, 8), 0, stream>>>(blk_mlp_w1, mlp1Wt, 128, 256);
  wtrans_k<<<dim3(8, 4, 5), dim3(32, 8), 0, stream>>>(blk_mlp_w2, mlp2Wt, 256, 128);

  // ---- PE encoder (fp32) ----
  concat_pe_k<<<(PEROWS * 35 + 255) / 256, 256, 0, stream>>>(node_feat, lapl, x35, PEROWS);
  rowgemm_k<16><<<dim3(512, 1), 128, 16 * 35 * 4, stream>>>(x35, pe_w1, pe_b1, nullptr, xa, PEROWS, 35, 70, 1, 0);
  rowgemm_k<16><<<dim3(512, 1), 128, 16 * 70 * 4, stream>>>(xa, pe_w2, pe_b2, nullptr, xb, PEROWS, 70, 70, 1, 0);
  rowgemm_k<16><<<dim3(512, 1), 128, 16 * 70 * 4, stream>>>(xb, pe_w3, pe_b3, nullptr, xa, PEROWS, 70, 70, 1, 0);
  ln_rows_k<<<(PEROWS * 64 + 255) / 256, 256, 0, stream>>>(xa, xb, nullptr, pe_lng, pe_lnb, nullptr, nullptr, nullptr, PEROWS, 70);
  rowgemm_k<16><<<dim3(512, 1), 128, 16 * 70 * 4, stream>>>(xb, pe_w4, pe_b4, nullptr, x, PEROWS, 70, DIMC, 0, 1);
  fill_cls_k<<<NB, DIMC, 0, stream>>>(cls_token, x);

  // ---- transformer layers ----
  const int lnGrid = (ROWS * 64 + 255) / 256;  // 2050
  for (int i = 0; i < 5; ++i) {
    const float* ln1g = blk_ln1_g + i * DIMC;
    const float* ln1b = blk_ln1_b + i * DIMC;
    const float* pb   = blk_proj_b + i * DIMC;
    const float* gw   = blk_gamma_w + (size_t)i * DIMC * 2;
    const float* gb   = blk_gamma_b + i * 2;
    const float* ln2g = blk_ln2_g + i * DIMC;
    const float* ln2b = blk_ln2_b + i * DIMC;
    const float* mb1  = blk_mlp_b1 + i * 256;
    const float* mb2  = blk_mlp_b2 + i * DIMC;
    const unsigned short* qw = qkvWt + (size_t)i * 393216;
    const unsigned short* pw = projWt + (size_t)i * 131072;
    const unsigned short* m1w = mlp1Wt + (size_t)i * 32768;
    const unsigned short* m2w = mlp2Wt + (size_t)i * 32768;

    ln_rows_k<<<lnGrid, 256, 0, stream>>>(x, h, hb, ln1g, ln1b, gw, gb, gam, ROWS, DIMC);
    mgemm_k<0, 1, 0><<<dim3(129, 48), 256, 0, stream>>>(hb, qw, nullptr, nullptr, qkv, ROWS, 128, 3072);
    vtrans_k<<<dim3(17, NHEADS, NB), 256, 0, stream>>>(qkv, vt);
    attn_mfma_k<<<dim3(NHEADS, 17, NB), 256, 0, stream>>>(qkv, gam, adjc, vt, obufb);
    mgemm_k<0, 0, 1><<<dim3(129, 2), 256, 0, stream>>>(obufb, pw, pb, h, x, ROWS, 1024, 128);
    ln_rows_k<<<lnGrid, 256, 0, stream>>>(x, h, hb, ln2g, ln2b, nullptr, nullptr, nullptr, ROWS, DIMC);
    mgemm_k<1, 1, 0><<<dim3(129, 4), 256, 0, stream>>>(hb, m1w, mb1, nullptr, hidb, ROWS, 128, 256);
    mgemm_k<0, 0, 1><<<dim3(129, 2), 256, 0, stream>>>(hidb, m2w, mb2, h, x, ROWS, 256, 128);
  }

  // ---- head (fp32) ----
  extract_cls_k<<<NB, DIMC, 0, stream>>>(x, s0);
  ln_rows_k<<<2, 256, 0, stream>>>(s0, s1, nullptr, head_lng, head_lnb, nullptr, nullptr, nullptr, NB, DIMC);
  rowgemm_k<8><<<dim3(1, 1), 128, 8 * 128 * 4, stream>>>(s1, head_w, head_b, nullptr, out_c, NB, DIMC, DIMC, 0, 0);
  rowgemm_k<8><<<dim3(1, 1), 128, 8 * 128 * 4, stream>>>(out_c, proj_w1, proj_b1, nullptr, s2, NB, DIMC, DIMC, 1, 0);
  rowgemm_k<8><<<dim3(1, 1), 128, 8 * 128 * 4, stream>>>(s2, proj_w2, proj_b2, nullptr, s3, NB, DIMC, DIMC, 1, 0);
  rowgemm_k<8><<<dim3(1, 1), 128, 8 * 128 * 4, stream>>>(s3, proj_w3, proj_b3, nullptr, s2, NB, DIMC, DIMC, 1, 0);
  ln_rows_k<<<2, 256, 0, stream>>>(s2, s3, nullptr, proj_lng, proj_lnb, nullptr, nullptr, nullptr, NB, DIMC);
  rowgemm_k<8><<<dim3(1, 4), 256, 8 * 128 * 4, stream>>>(s3, proj_w4, proj_b4, nullptr, out_p, NB, DIMC, 1000, 0, 0);
}

// Round 7
// 1601.152 us; speedup vs baseline: 1.5557x; 1.1659x over previous
//
#include <hip/hip_runtime.h>
#include <hip/hip_bf16.h>
#include <math.h>

// Problem constants
#define NB 8
#define NSEQ 1024
#define M_ 1025                 // NSEQ + 1 (cls)
#define ROWS (NB * M_)          // 8200
#define DIMC 128
#define NHEADS 8
#define QKV3 3072               // 3*8*128
#define PEROWS (NB * NSEQ)      // 8192
#define ACS 1088                // adj_cls padded column stride

typedef __attribute__((ext_vector_type(8))) short bf16x8;
typedef __attribute__((ext_vector_type(4))) float f32x4;

__device__ __forceinline__ float gelu_f(float x) {
  return 0.5f * x * (1.f + erff(x * 0.70710678118654752440f));
}

__device__ __forceinline__ unsigned short f2bf(float f) {
  __hip_bfloat16 h = __float2bfloat16(f);
  return *reinterpret_cast<unsigned short*>(&h);
}

__device__ __forceinline__ float bf2f(unsigned short u) {
  union { unsigned int i; float f; } c;
  c.i = ((unsigned int)u) << 16;
  return c.f;
}

// ---------------------------------------------------------------------------
// fp32 row-tiled GEMM (PE encoder + head only)
// ---------------------------------------------------------------------------
template<int TR>
__global__ __launch_bounds__(256) void rowgemm_k(
    const float* __restrict__ in, const float* __restrict__ W,
    const float* __restrict__ bias, const float* __restrict__ res,
    float* __restrict__ out, int rows, int K, int Nout, int act, int remap)
{
  extern __shared__ float s_in[];
  const int tid = threadIdx.x;
  const int r0 = blockIdx.x * TR;
  const int tot = TR * K;
  for (int idx = tid; idx < tot; idx += blockDim.x) {
    int r = idx / K;
    int k = idx - r * K;
    int gr = r0 + r;
    s_in[idx] = (gr < rows) ? in[(size_t)gr * K + k] : 0.f;
  }
  __syncthreads();
  const int j = blockIdx.y * blockDim.x + tid;
  if (j >= Nout) return;
  float acc[TR];
  const float bv = bias ? bias[j] : 0.f;
#pragma unroll
  for (int r = 0; r < TR; ++r) acc[r] = bv;
  for (int k = 0; k < K; ++k) {
    const float w = W[(size_t)k * Nout + j];
#pragma unroll
    for (int r = 0; r < TR; ++r) acc[r] = fmaf(s_in[r * K + k], w, acc[r]);
  }
  for (int r = 0; r < TR; ++r) {
    const int gr = r0 + r;
    if (gr >= rows) break;
    float v = acc[r];
    if (act == 1) v = gelu_f(v);
    if (res) v += res[(size_t)gr * Nout + j];
    const size_t orow = remap ? (size_t)(gr + gr / 1024 + 1) : (size_t)gr;
    out[orow * (size_t)Nout + j] = v;
  }
}

// ---------------------------------------------------------------------------
// bf16 MFMA GEMM: out = [act]( Xb @ Wt^T + bias ) [+ res]
// ---------------------------------------------------------------------------
template<int ACT, int OBF, int RES>
__global__ __launch_bounds__(256) void mgemm_k(
    const unsigned short* __restrict__ Xb, const unsigned short* __restrict__ Wt,
    const float* __restrict__ bias, const float* __restrict__ res,
    void* __restrict__ outp, int rows, int K, int N)
{
  __shared__ unsigned short sX[64][72];
  __shared__ unsigned short sW[64][72];
  const int tid = threadIdx.x;
  const int w = tid >> 6, lane = tid & 63;
  const int col = lane & 15, quad = lane >> 4;
  const int r0 = blockIdx.x * 64, n0 = blockIdx.y * 64;
  const int lr = tid >> 2, lc = tid & 3;
  const int xrow = min(r0 + lr, rows - 1);
  const unsigned short* xsrc = Xb + (size_t)xrow * K + lc * 8;
  const unsigned short* wsrc = Wt + (size_t)(n0 + lr) * K + lc * 8;

  f32x4 acc[4];
#pragma unroll
  for (int t = 0; t < 4; ++t) acc[t] = (f32x4){0.f, 0.f, 0.f, 0.f};

  for (int k0 = 0; k0 < K; k0 += 64) {
    __syncthreads();
    *(uint4*)&sX[lr][lc * 8]      = *(const uint4*)(xsrc + k0);
    *(uint4*)&sX[lr][lc * 8 + 32] = *(const uint4*)(xsrc + k0 + 32);
    *(uint4*)&sW[lr][lc * 8]      = *(const uint4*)(wsrc + k0);
    *(uint4*)&sW[lr][lc * 8 + 32] = *(const uint4*)(wsrc + k0 + 32);
    __syncthreads();
    const bf16x8 aX0 = *(const bf16x8*)&sX[w * 16 + col][quad * 8];
    const bf16x8 aX1 = *(const bf16x8*)&sX[w * 16 + col][32 + quad * 8];
#pragma unroll
    for (int t = 0; t < 4; ++t) {
      const bf16x8 bW0 = *(const bf16x8*)&sW[t * 16 + col][quad * 8];
      const bf16x8 bW1 = *(const bf16x8*)&sW[t * 16 + col][32 + quad * 8];
      acc[t] = __builtin_amdgcn_mfma_f32_16x16x32_bf16(aX0, bW0, acc[t], 0, 0, 0);
      acc[t] = __builtin_amdgcn_mfma_f32_16x16x32_bf16(aX1, bW1, acc[t], 0, 0, 0);
    }
  }
  const int gr_base = r0 + w * 16 + quad * 4;
#pragma unroll
  for (int t = 0; t < 4; ++t) {
    const int n = n0 + t * 16 + col;
    const float bv = bias ? bias[n] : 0.f;
#pragma unroll
    for (int r = 0; r < 4; ++r) {
      const int gr = gr_base + r;
      if (gr < rows) {
        float v = acc[t][r] + bv;
        if (ACT) v = gelu_f(v);
        if (RES) v += res[(size_t)gr * N + n];
        if (OBF) ((unsigned short*)outp)[(size_t)gr * N + n] = f2bf(v);
        else     ((float*)outp)[(size_t)gr * N + n] = v;
      }
    }
  }
}

// ---------------------------------------------------------------------------
// Wave-per-row LayerNorm; optional bf16 shadow out; optional fused gamma
// ---------------------------------------------------------------------------
__global__ __launch_bounds__(256) void ln_rows_k(
    const float* __restrict__ in, float* __restrict__ out,
    unsigned short* __restrict__ outb,
    const float* __restrict__ g, const float* __restrict__ b,
    const float* __restrict__ gw, const float* __restrict__ gb,
    float* __restrict__ gamout, int rows, int D)
{
  const int wv = (blockIdx.x * blockDim.x + threadIdx.x) >> 6;
  const int lane = threadIdx.x & 63;
  if (wv >= rows) return;
  const float* r = in + (size_t)wv * D;
  float s = 0.f;
  for (int d = lane; d < D; d += 64) s += r[d];
  for (int off = 32; off; off >>= 1) s += __shfl_down(s, off);
  const float mean = __shfl(s, 0) / (float)D;
  float v = 0.f;
  for (int d = lane; d < D; d += 64) { float t = r[d] - mean; v += t * t; }
  for (int off = 32; off; off >>= 1) v += __shfl_down(v, off);
  const float inv = rsqrtf(__shfl(v, 0) / (float)D + 1e-5f);
  float* orow = out + (size_t)wv * D;
  float a0 = 0.f, a1 = 0.f;
  for (int d = lane; d < D; d += 64) {
    const float o = (r[d] - mean) * inv * g[d] + b[d];
    orow[d] = o;
    if (outb) outb[(size_t)wv * D + d] = f2bf(o);
    if (gw) { a0 = fmaf(o, gw[2 * d], a0); a1 = fmaf(o, gw[2 * d + 1], a1); }
  }
  if (gw) {
    for (int off = 32; off; off >>= 1) { a0 += __shfl_down(a0, off); a1 += __shfl_down(a1, off); }
    if (lane == 0) {
      gamout[(size_t)wv * 2 + 0] = expf(a0 + gb[0]);
      gamout[(size_t)wv * 2 + 1] = expf(a1 + gb[1]);
    }
  }
}

// ---------------------------------------------------------------------------
// prep: bf16 adj_cls matrix (M_ x ACS per batch, zero-padded)
// ---------------------------------------------------------------------------
__global__ void adjc_k(const float* __restrict__ adj, unsigned short* __restrict__ adjc)
{
  const int n = blockIdx.x;   // 0..1024
  const int b = blockIdx.y;
  unsigned short* row = adjc + ((size_t)b * M_ + n) * ACS;
  const float* ar = (n >= 1) ? adj + ((size_t)b * NSEQ + (n - 1)) * NSEQ : nullptr;
  for (int m = threadIdx.x; m < ACS; m += 256) {
    float v = 0.f;
    if (n == 0) v = (m == 0) ? 1.f : 0.f;
    else if (m >= 1 && m <= NSEQ) v = ar[m - 1];
    row[m] = f2bf(v);
  }
}

// ---------------------------------------------------------------------------
// prep: Wt[n][k] = bf16(W[k][n])
// ---------------------------------------------------------------------------
__global__ void wtrans_k(const float* __restrict__ W, unsigned short* __restrict__ Wt,
                         int K, int N)
{
  __shared__ float t[32][33];
  const int k0 = blockIdx.x * 32, n0 = blockIdx.y * 32;
  const float* Wd = W + (size_t)blockIdx.z * K * N;
  unsigned short* Wtd = Wt + (size_t)blockIdx.z * K * N;
  for (int i = threadIdx.y; i < 32; i += 8)
    t[i][threadIdx.x] = Wd[(size_t)(k0 + i) * N + n0 + threadIdx.x];
  __syncthreads();
  for (int i = threadIdx.y; i < 32; i += 8)
    Wtd[(size_t)(n0 + i) * K + k0 + threadIdx.x] = f2bf(t[threadIdx.x][i]);
}

// ---------------------------------------------------------------------------
// bf16 MFMA flash attention, Q-tile 64 (4 waves x 16 rows), K-tile 64.
// grid (8=heads, 17=qtile, 8=batch), block 256.
// NO online softmax: scores are bounded (|s| <~ 10), so p = exp(s) directly,
// l accumulated per-lane across tiles, one butterfly reduce at the end.
// adj bias read straight from global (L2) - off the LDS pipe.
// sVt swizzle (R4): elem (m, d) at sVt[d][(((m>>3) ^ ((d>>3)&7))*8) | (m&7)].
// sP swizzle: P[q][key] at sP[q][(((key>>3) ^ (q&7))*8) | (key&7)].
// ---------------------------------------------------------------------------
__global__ __launch_bounds__(256) void attn_mfma_k(
    const unsigned short* __restrict__ qkv, const float* __restrict__ gamma,
    const unsigned short* __restrict__ adjc, unsigned short* __restrict__ o)
{
  __shared__ unsigned short sK[64][136];   // keys row-major, pad 8
  __shared__ unsigned short sVt[128][72];  // transposed V, swizzled
  __shared__ unsigned short sP[64][72];    // P, swizzled

  const int hh = blockIdx.x, qt = blockIdx.y, b = blockIdx.z;
  const int tid = threadIdx.x;
  const int w = tid >> 6;
  const int lane = tid & 63;
  const int col = lane & 15;
  const int quad = lane >> 4;
  const int n0 = qt * 64;
  const int qbase = n0 + w * 16;
  const float scale = 0.088388347648318447f;  // 128^-0.5

  // Q fragments (registers, direct global)
  bf16x8 aQ[4];
  {
    const int qrow = min(qbase + col, 1024);
    const unsigned short* qp = qkv + ((size_t)(b * M_ + qrow)) * QKV3 + hh * DIMC + quad * 8;
#pragma unroll
    for (int c = 0; c < 4; ++c) aQ[c] = *(const bf16x8*)(qp + c * 32);
  }
  float g0[4], g1[4];
  const unsigned short* adjr[4];
#pragma unroll
  for (int r = 0; r < 4; ++r) {
    const int nc = min(qbase + quad * 4 + r, 1024);
    g0[r] = gamma[(size_t)(b * M_ + nc) * 2 + 0] * scale;
    g1[r] = gamma[(size_t)(b * M_ + nc) * 2 + 1];
    adjr[r] = adjc + ((size_t)b * M_ + nc) * ACS;
  }

  float l_i[4] = {0.f, 0.f, 0.f, 0.f};
  f32x4 Oacc[8];
#pragma unroll
  for (int t = 0; t < 8; ++t) Oacc[t] = (f32x4){0.f, 0.f, 0.f, 0.f};

  for (int kt = 0; kt < 17; ++kt) {
    const int m0 = kt * 64;
    __syncthreads();
    // stage K rows (vector) + V transpose (scalar b16, swizzled)
#pragma unroll
    for (int l = 0; l < 4; ++l) {
      const int idx = l * 256 + tid;
      const int m = idx >> 4, c = idx & 15;
      const int gm = m0 + m;
      uint4 kv = make_uint4(0u, 0u, 0u, 0u), vv = make_uint4(0u, 0u, 0u, 0u);
      if (gm < M_) {
        const unsigned short* base = qkv + ((size_t)(b * M_ + gm)) * QKV3 + hh * DIMC + c * 8;
        kv = *(const uint4*)(base + 1024);
        vv = *(const uint4*)(base + 2048);
      }
      *(uint4*)&sK[m][c * 8] = kv;
      union { uint4 u; unsigned short s[8]; } vu; vu.u = vv;
      const int swcol = (((m >> 3) ^ (c & 7)) << 3) | (m & 7);
#pragma unroll
      for (int j = 0; j < 8; ++j) sVt[c * 8 + j][swcol] = vu.s[j];
    }
    __syncthreads();

    // S = Q K^T
    f32x4 Sacc[4];
#pragma unroll
    for (int t = 0; t < 4; ++t) Sacc[t] = (f32x4){0.f, 0.f, 0.f, 0.f};
#pragma unroll
    for (int t = 0; t < 4; ++t) {
#pragma unroll
      for (int c = 0; c < 4; ++c) {
        const bf16x8 bK = *(const bf16x8*)&sK[t * 16 + col][c * 32 + quad * 8];
        Sacc[t] = __builtin_amdgcn_mfma_f32_16x16x32_bf16(aQ[c], bK, Sacc[t], 0, 0, 0);
      }
    }

    // p = exp(g0*S + g1*adj) (no max subtraction); write P to LDS, acc l
#pragma unroll
    for (int t = 0; t < 4; ++t) {
      const int m = m0 + t * 16 + col;
      const bool mv = (m < M_);
      const int chb = t * 2 + (col >> 3);
#pragma unroll
      for (int r = 0; r < 4; ++r) {
        const float av = bf2f(adjr[r][m]);           // global, L2-resident
        const float s = fmaf(g0[r], Sacc[t][r], g1[r] * av);
        const float pv = mv ? __expf(s) : 0.f;
        l_i[r] += pv;
        const int ql = w * 16 + quad * 4 + r;
        sP[ql][((chb ^ (ql & 7)) * 8) + (col & 7)] = f2bf(pv);
      }
    }

    // O += P V (own-wave P rows; swizzled reads, no barrier)
#pragma unroll
    for (int ch = 0; ch < 2; ++ch) {
      const int r0a = w * 16 + col;
      const bf16x8 aP = *(const bf16x8*)&sP[r0a][(((ch * 4 + quad) ^ (col & 7)) * 8)];
#pragma unroll
      for (int t = 0; t < 8; ++t) {
        const int pc = (ch * 4 + quad) ^ ((t * 2 + (col >> 3)) & 7);
        const bf16x8 bV = *(const bf16x8*)&sVt[t * 16 + col][pc * 8];
        Oacc[t] = __builtin_amdgcn_mfma_f32_16x16x32_bf16(aP, bV, Oacc[t], 0, 0, 0);
      }
    }
  }

  // epilogue: reduce l across the 16-lane col group, O /= l, bf16 out
#pragma unroll
  for (int r = 0; r < 4; ++r) {
    float s = l_i[r];
    s += __shfl_xor(s, 1);
    s += __shfl_xor(s, 2);
    s += __shfl_xor(s, 4);
    s += __shfl_xor(s, 8);
    const int n = qbase + quad * 4 + r;
    if (n < M_) {
      const float invl = 1.f / s;
      unsigned short* orow = o + ((size_t)(b * M_ + n)) * (NHEADS * DIMC) + hh * DIMC + col;
#pragma unroll
      for (int t = 0; t < 8; ++t) orow[t * 16] = f2bf(Oacc[t][r] * invl);
    }
  }
}

// ---------------------------------------------------------------------------
// small utility kernels
// ---------------------------------------------------------------------------
__global__ void concat_pe_k(const float* __restrict__ nf, const float* __restrict__ lp,
                            float* __restrict__ x35, int rows)
{
  const int idx = blockIdx.x * blockDim.x + threadIdx.x;
  if (idx >= rows * 35) return;
  const int r = idx / 35, c = idx - r * 35;
  x35[idx] = (c < 3) ? nf[(size_t)r * 3 + c] : lp[(size_t)r * 32 + (c - 3)];
}

__global__ void fill_cls_k(const float* __restrict__ cls, float* __restrict__ x)
{
  x[(size_t)blockIdx.x * M_ * DIMC + threadIdx.x] = cls[threadIdx.x];
}

__global__ void extract_cls_k(const float* __restrict__ x, float* __restrict__ c0)
{
  c0[(size_t)blockIdx.x * DIMC + threadIdx.x] = x[(size_t)blockIdx.x * M_ * DIMC + threadIdx.x];
}

// ---------------------------------------------------------------------------
extern "C" void kernel_launch(void* const* d_in, const int* in_sizes, int n_in,
                              void* d_out, int out_size, void* d_ws, size_t ws_size,
                              hipStream_t stream)
{
  (void)in_sizes; (void)n_in; (void)out_size; (void)ws_size;
  const float* node_feat = (const float*)d_in[0];
  const float* adj       = (const float*)d_in[1];
  const float* lapl      = (const float*)d_in[2];
  const float* cls_token = (const float*)d_in[3];
  const float* pe_w1 = (const float*)d_in[4];
  const float* pe_b1 = (const float*)d_in[5];
  const float* pe_w2 = (const float*)d_in[6];
  const float* pe_b2 = (const float*)d_in[7];
  const float* pe_w3 = (const float*)d_in[8];
  const float* pe_b3 = (const float*)d_in[9];
  const float* pe_lng = (const float*)d_in[10];
  const float* pe_lnb = (const float*)d_in[11];
  const float* pe_w4 = (const float*)d_in[12];
  const float* pe_b4 = (const float*)d_in[13];
  const float* blk_ln1_g = (const float*)d_in[14];
  const float* blk_ln1_b = (const float*)d_in[15];
  const float* blk_qkv_w = (const float*)d_in[16];
  const float* blk_proj_w = (const float*)d_in[17];
  const float* blk_proj_b = (const float*)d_in[18];
  const float* blk_gamma_w = (const float*)d_in[19];
  const float* blk_gamma_b = (const float*)d_in[20];
  const float* blk_ln2_g = (const float*)d_in[21];
  const float* blk_ln2_b = (const float*)d_in[22];
  const float* blk_mlp_w1 = (const float*)d_in[23];
  const float* blk_mlp_b1 = (const float*)d_in[24];
  const float* blk_mlp_w2 = (const float*)d_in[25];
  const float* blk_mlp_b2 = (const float*)d_in[26];
  const float* head_lng = (const float*)d_in[27];
  const float* head_lnb = (const float*)d_in[28];
  const float* head_w = (const float*)d_in[29];
  const float* head_b = (const float*)d_in[30];
  const float* proj_w1 = (const float*)d_in[31];
  const float* proj_b1 = (const float*)d_in[32];
  const float* proj_w2 = (const float*)d_in[33];
  const float* proj_b2 = (const float*)d_in[34];
  const float* proj_w3 = (const float*)d_in[35];
  const float* proj_b3 = (const float*)d_in[36];
  const float* proj_lng = (const float*)d_in[37];
  const float* proj_lnb = (const float*)d_in[38];
  const float* proj_w4 = (const float*)d_in[39];
  const float* proj_b4 = (const float*)d_in[40];

  // ---- workspace layout ----
  float* ws   = (float*)d_ws;
  float* x    = ws;                        // 1,049,600 f
  float* h    = x + 1049600;               // 1,049,600 f
  float* gam  = h + 1049600;               // 16,400 f
  float* obuf = gam + 16400;               // 5,248,000 f region
  unsigned short* obufb = (unsigned short*)obuf;             // 8200*1024 bf16
  unsigned short* hidb  = (unsigned short*)(obuf + 4198400); // 8200*256 bf16
  float* x35 = obuf;                        // PE scratch (pre-layers)
  float* xa  = obuf + 300000;
  float* xb  = obuf + 900000;
  float* sm  = obuf + 5248000;             // 8,192 f
  unsigned short* hb   = (unsigned short*)(sm + 8192);       // 8200*128 bf16
  unsigned short* qkv  = hb + 1049600;     // 25,190,400 us
  unsigned short* adjc = qkv + 25190400;   // 8,921,600 us
  unsigned short* qkvWt = adjc + 8921600;  // 5*393216
  unsigned short* projWt = qkvWt + 5 * 393216;
  unsigned short* mlp1Wt = projWt + 5 * 131072;
  unsigned short* mlp2Wt = mlp1Wt + 5 * 32768;
  float* s0 = sm, *s1 = sm + 1024, *s2 = sm + 2048, *s3 = sm + 3072;

  float* out_c = (float*)d_out;            // (8,128)
  float* out_p = out_c + NB * DIMC;        // (8,1000)

  // ---- prep ----
  adjc_k<<<dim3(M_, NB), 256, 0, stream>>>(adj, adjc);
  wtrans_k<<<dim3(4, 96, 5), dim3(32, 8), 0, stream>>>(blk_qkv_w, qkvWt, 128, 3072);
  wtrans_k<<<dim3(32, 4, 5), dim3(32, 8), 0, stream>>>(blk_proj_w, projWt, 1024, 128);
  wtrans_k<<<dim3(4, 8, 5), dim3(32, 8), 0, stream>>>(blk_mlp_w1, mlp1Wt, 128, 256);
  wtrans_k<<<dim3(8, 4, 5), dim3(32, 8), 0, stream>>>(blk_mlp_w2, mlp2Wt, 256, 128);

  // ---- PE encoder (fp32) ----
  concat_pe_k<<<(PEROWS * 35 + 255) / 256, 256, 0, stream>>>(node_feat, lapl, x35, PEROWS);
  rowgemm_k<16><<<dim3(512, 1), 128, 16 * 35 * 4, stream>>>(x35, pe_w1, pe_b1, nullptr, xa, PEROWS, 35, 70, 1, 0);
  rowgemm_k<16><<<dim3(512, 1), 128, 16 * 70 * 4, stream>>>(xa, pe_w2, pe_b2, nullptr, xb, PEROWS, 70, 70, 1, 0);
  rowgemm_k<16><<<dim3(512, 1), 128, 16 * 70 * 4, stream>>>(xb, pe_w3, pe_b3, nullptr, xa, PEROWS, 70, 70, 1, 0);
  ln_rows_k<<<(PEROWS * 64 + 255) / 256, 256, 0, stream>>>(xa, xb, nullptr, pe_lng, pe_lnb, nullptr, nullptr, nullptr, PEROWS, 70);
  rowgemm_k<16><<<dim3(512, 1), 128, 16 * 70 * 4, stream>>>(xb, pe_w4, pe_b4, nullptr, x, PEROWS, 70, DIMC, 0, 1);
  fill_cls_k<<<NB, DIMC, 0, stream>>>(cls_token, x);

  // ---- transformer layers ----
  const int lnGrid = (ROWS * 64 + 255) / 256;  // 2050
  for (int i = 0; i < 5; ++i) {
    const float* ln1g = blk_ln1_g + i * DIMC;
    const float* ln1b = blk_ln1_b + i * DIMC;
    const float* pb   = blk_proj_b + i * DIMC;
    const float* gw   = blk_gamma_w + (size_t)i * DIMC * 2;
    const float* gb   = blk_gamma_b + i * 2;
    const float* ln2g = blk_ln2_g + i * DIMC;
    const float* ln2b = blk_ln2_b + i * DIMC;
    const float* mb1  = blk_mlp_b1 + i * 256;
    const float* mb2  = blk_mlp_b2 + i * DIMC;
    const unsigned short* qw = qkvWt + (size_t)i * 393216;
    const unsigned short* pw = projWt + (size_t)i * 131072;
    const unsigned short* m1w = mlp1Wt + (size_t)i * 32768;
    const unsigned short* m2w = mlp2Wt + (size_t)i * 32768;

    ln_rows_k<<<lnGrid, 256, 0, stream>>>(x, h, hb, ln1g, ln1b, gw, gb, gam, ROWS, DIMC);
    mgemm_k<0, 1, 0><<<dim3(129, 48), 256, 0, stream>>>(hb, qw, nullptr, nullptr, qkv, ROWS, 128, 3072);
    attn_mfma_k<<<dim3(NHEADS, 17, NB), 256, 0, stream>>>(qkv, gam, adjc, obufb);
    mgemm_k<0, 0, 1><<<dim3(129, 2), 256, 0, stream>>>(obufb, pw, pb, h, x, ROWS, 1024, 128);
    ln_rows_k<<<lnGrid, 256, 0, stream>>>(x, h, hb, ln2g, ln2b, nullptr, nullptr, nullptr, ROWS, DIMC);
    mgemm_k<1, 1, 0><<<dim3(129, 4), 256, 0, stream>>>(hb, m1w, mb1, nullptr, hidb, ROWS, 128, 256);
    mgemm_k<0, 0, 1><<<dim3(129, 2), 256, 0, stream>>>(hidb, m2w, mb2, h, x, ROWS, 256, 128);
  }

  // ---- head (fp32) ----
  extract_cls_k<<<NB, DIMC, 0, stream>>>(x, s0);
  ln_rows_k<<<2, 256, 0, stream>>>(s0, s1, nullptr, head_lng, head_lnb, nullptr, nullptr, nullptr, NB, DIMC);
  rowgemm_k<8><<<dim3(1, 1), 128, 8 * 128 * 4, stream>>>(s1, head_w, head_b, nullptr, out_c, NB, DIMC, DIMC, 0, 0);
  rowgemm_k<8><<<dim3(1, 1), 128, 8 * 128 * 4, stream>>>(out_c, proj_w1, proj_b1, nullptr, s2, NB, DIMC, DIMC, 1, 0);
  rowgemm_k<8><<<dim3(1, 1), 128, 8 * 128 * 4, stream>>>(s2, proj_w2, proj_b2, nullptr, s3, NB, DIMC, DIMC, 1, 0);
  rowgemm_k<8><<<dim3(1, 1), 128, 8 * 128 * 4, stream>>>(s3, proj_w3, proj_b3, nullptr, s2, NB, DIMC, DIMC, 1, 0);
  ln_rows_k<<<2, 256, 0, stream>>>(s2, s3, nullptr, proj_lng, proj_lnb, nullptr, nullptr, nullptr, NB, DIMC);
  rowgemm_k<8><<<dim3(1, 4), 256, 8 * 128 * 4, stream>>>(s3, proj_w4, proj_b4, nullptr, out_p, NB, DIMC, 1000, 0, 0);
}